// Round 5
// baseline (1081.760 us; speedup 1.0000x reference)
//
#include <hip/hip_runtime.h>
#include <cstdint>

typedef unsigned short ushort_t;
typedef __bf16 bf16x8 __attribute__((ext_vector_type(8)));
typedef float f32x4 __attribute__((ext_vector_type(4)));

__device__ __forceinline__ unsigned short f2bf(float f) {
  unsigned u = __builtin_bit_cast(unsigned, f);
  u += 0x7FFFu + ((u >> 16) & 1u);   // RNE
  return (unsigned short)(u >> 16);
}
__device__ __forceinline__ float bflo(unsigned u) {  // low bf16 -> f32
  return __builtin_bit_cast(float, u << 16);
}
__device__ __forceinline__ float bfhi(unsigned u) {  // high bf16 -> f32
  return __builtin_bit_cast(float, u & 0xFFFF0000u);
}
// async global->LDS, 16B/lane; LDS dest = wave-uniform base + lane*16
__device__ __forceinline__ void gld16(const void* g, void* l) {
  auto* gp = reinterpret_cast<const __attribute__((address_space(1))) unsigned*>(
      reinterpret_cast<uintptr_t>(g));
  auto* lp = reinterpret_cast<__attribute__((address_space(3))) unsigned*>(
      reinterpret_cast<uintptr_t>(l));
  __builtin_amdgcn_global_load_lds(gp, lp, 16, 0, 0);
}

// ---------------------------------------------------------------------------
// prep_all: UNCHANGED (control).
// ---------------------------------------------------------------------------
__global__ __launch_bounds__(256) void prep_all(
    const float* __restrict__ x, const float* __restrict__ Wq,
    const float* __restrict__ Wk, const float* __restrict__ Wv,
    const float* __restrict__ bq, const float* __restrict__ bk,
    const float* __restrict__ bv, ushort_t* __restrict__ Ax,
    ushort_t* __restrict__ Wt, float* __restrict__ bias) {
  __shared__ ushort_t red[64][65];
  const int b = blockIdx.x;
  const int tid = threadIdx.x;
  if (b < 3072) {
    const int ntile = b % 48, ktile = b / 48;
    const int n0 = ntile * 64, k0 = ktile * 64;
    if (ntile < 16) {
      for (int i = tid; i < 64 * 64; i += 256) {
        const int kk = i >> 6, nn = i & 63;
        const float4 w = *reinterpret_cast<const float4*>(
            Wq + (size_t)(k0 + kk) * 4096 + (size_t)(n0 + nn) * 4);
        red[kk][nn] = f2bf(w.x + w.y + w.z + w.w);
      }
    } else {
      const float* W = (ntile < 32) ? Wk : Wv;
      const int nb = (ntile < 32) ? (n0 - 1024) : (n0 - 2048);
      for (int i = tid; i < 64 * 64; i += 256) {
        const int kk = i >> 6, nn = i & 63;
        red[kk][nn] = f2bf(W[(size_t)(k0 + kk) * 1024 + nb + nn]);
      }
    }
    __syncthreads();
    for (int i = tid; i < 64 * 64; i += 256) {
      const int kk = i & 63, nn = i >> 6;  // coalesced along k
      Wt[(size_t)(n0 + nn) * 4096 + k0 + kk] = red[kk][nn];
    }
  } else if (b < 11264) {
    const size_t i = ((size_t)(b - 3072) * 256 + tid) * 8;
    const float4 a = *reinterpret_cast<const float4*>(x + i);
    const float4 c = *reinterpret_cast<const float4*>(x + i + 4);
    union { ushort_t u[8]; uint4 v; } pk;
    pk.u[0] = f2bf(a.x); pk.u[1] = f2bf(a.y); pk.u[2] = f2bf(a.z); pk.u[3] = f2bf(a.w);
    pk.u[4] = f2bf(c.x); pk.u[5] = f2bf(c.y); pk.u[6] = f2bf(c.z); pk.u[7] = f2bf(c.w);
    *reinterpret_cast<uint4*>(Ax + i) = pk.v;
  } else {
    const int n = (b - 11264) * 256 + tid;  // 0..3071
    float v;
    if (n < 1024) {
      const float4 w = *reinterpret_cast<const float4*>(bq + (size_t)n * 4);
      v = w.x + w.y + w.z + w.w;
    } else if (n < 2048) {
      v = bk[n - 1024];
    } else {
      v = bv[n - 2048];
    }
    bias[n] = v;
  }
}

// ---------------------------------------------------------------------------
// gemm_qkv v6: R4's verified 256x192 / k-split geometry; schedule changed to
// a wave-level software pipeline that overlaps frag ds_reads with MFMAs.
// R4 cycle audit: tile = 3660 cy = MFMA(1862) + LDS(1800) fully SERIAL,
// because each wave's reads preceded its own MFMAs (lgkm dep) and all waves
// are barrier-locked to the same phase. v6 per iteration t:
//   drain(vm+lgkm); barrier;        // publishes buf[(t+1)&1]
//   stage(t+2) -> buf[t&1]          // race-free: lgkm drain + barrier means
//                                   // ALL waves' reads of buf[t&1] retired
//   read F(t+1) (14 ds_read)        // no consumer this iteration
//   48 MFMA on F(t) (regs)          // reads execute UNDER these
// Stage->drain distance = full iteration (~1900cy) -> no vm stall.
// F(t),F(t+1) both live: ~112 VGPR frags + acc in AGPR (192) ~= 350/wave,
// fits 2 waves/SIMD. Static frag indexing via 2x-unrolled loop.
// ---------------------------------------------------------------------------
#define WAITV0() asm volatile("s_waitcnt vmcnt(0)" ::: "memory")
#define DRAIN() asm volatile("s_waitcnt vmcnt(0) lgkmcnt(0)" ::: "memory")
#define BARRIER()                         \
  do {                                    \
    __builtin_amdgcn_s_barrier();         \
    asm volatile("" ::: "memory");        \
    __builtin_amdgcn_sched_barrier(0);    \
  } while (0)

struct Frags {
  bf16x8 a[8];
  bf16x8 b[6];
};

__global__ __launch_bounds__(512, 2) void gemm_qkv(const ushort_t* __restrict__ A,
                                                   const ushort_t* __restrict__ Bt,
                                                   const float* __restrict__ bias,
                                                   ushort_t* __restrict__ C) {
  __shared__ char smem[114688];                      // As 64K | Bs 48K ; reused as f32 scratch
  ushort_t* AsBuf = reinterpret_cast<ushort_t*>(smem);            // [2][16384]
  ushort_t* BsBuf = reinterpret_cast<ushort_t*>(smem + 65536);    // [2][12288]
  const int tid = threadIdx.x;
  const int lane = tid & 63, wave = tid >> 6;  // 8 waves

  // bijective XCD swizzle (256 blocks, 256 % 8 == 0)
  const int id = blockIdx.x;
  const int wg = (id & 7) * 32 + (id >> 3);
  const int M0 = (wg >> 4) * 256, N0 = (wg & 15) * 192;

  const int rik = lane >> 3;         // row within 8-row chunk
  const int gch = (lane & 7) ^ rik;  // pre-swizzled global k-chunk (involution)
  const ushort_t* aG = A + (size_t)(M0 + wave * 32 + rik) * 4096 + gch * 8;
  const ushort_t* bG = Bt + (size_t)(N0 + wave * 24 + rik) * 4096 + gch * 8;

  const int kh = wave & 1, wq = wave >> 1;   // k-half | output quadrant
  const int wm = wq >> 1, wn = wq & 1;       // 2M x 2N
  const int quad = lane >> 4, l15 = lane & 15;

  // fragment LDS byte offsets: row*128 + phys_chunk*16; row&7 == l15&7
  const int ch = ((kh * 4 + quad) ^ (l15 & 7)) * 16;
  const int abase = (wm * 128 + l15) * 128 + ch;  // + mi*2048
  const int bbase = (wn * 96 + l15) * 128 + ch;   // + ni*2048

  f32x4 acc[8][6];
  const f32x4 z = {0.f, 0.f, 0.f, 0.f};
#pragma unroll
  for (int mi = 0; mi < 8; ++mi)
#pragma unroll
    for (int ni = 0; ni < 6; ++ni) acc[mi][ni] = z;

  auto stage = [&](int bb, int kt) {
    const int ko = kt * 64;
    ushort_t* asb = AsBuf + bb * 16384;
    ushort_t* bsb = BsBuf + bb * 12288;
#pragma unroll
    for (int q = 0; q < 4; ++q)  // A rows wave*32 + q*8 + rik
      gld16(aG + ko + (size_t)q * (8 * 4096), asb + (wave * 4 + q) * 512);
#pragma unroll
    for (int q = 0; q < 3; ++q)  // B rows wave*24 + q*8 + rik
      gld16(bG + ko + (size_t)q * (8 * 4096), bsb + (wave * 3 + q) * 512);
  };
  auto ldFrags = [&](Frags& F, int bb) {
    const char* ab = reinterpret_cast<const char*>(AsBuf + bb * 16384);
    const char* bbp = reinterpret_cast<const char*>(BsBuf + bb * 12288);
#pragma unroll
    for (int mi = 0; mi < 8; ++mi)
      F.a[mi] = *reinterpret_cast<const bf16x8*>(ab + abase + mi * 2048);
#pragma unroll
    for (int ni = 0; ni < 6; ++ni)
      F.b[ni] = *reinterpret_cast<const bf16x8*>(bbp + bbase + ni * 2048);
  };
  auto mmqAll = [&](const Frags& F) {
#pragma unroll
    for (int ni = 0; ni < 6; ++ni) {
      __builtin_amdgcn_s_setprio(1);
#pragma unroll
      for (int mi = 0; mi < 8; ++mi)
        acc[mi][ni] =
            __builtin_amdgcn_mfma_f32_16x16x32_bf16(F.a[mi], F.b[ni], acc[mi][ni], 0, 0, 0);
      __builtin_amdgcn_s_setprio(0);
    }
  };
  // iteration t: publish tile t+1, stage tile t+2, read F(t+1), MFMA F(t)
  auto body = [&](int t, Frags& Fc, Frags& Fn) {
    DRAIN();    // own stage(t+1) landed (issued a full iter ago) + own frag
    BARRIER();  // reads retired -> buf[t&1] overwrite below is race-free
    if (t + 2 <= 63) stage(t & 1, t + 2);  // (t+2)&1 == t&1
    ldFrags(Fn, (t + 1) & 1);
    mmqAll(Fc);
  };

  Frags F0, F1;
  // prologue: stage tile0 -> buf0; publish; read F0; issue stage tile1.
  stage(0, 0);
  WAITV0();
  BARRIER();
  ldFrags(F0, 0);
  stage(1, 1);

  for (int t = 0; t < 62; t += 2) {
    body(t, F0, F1);
    body(t + 1, F1, F0);
  }
  body(62, F0, F1);  // reads F(63) into F1
  DRAIN();           // frag reads of F1 retired before final use
  mmqAll(F1);        // tile 63

  // ---- epilogue: reduce k-halves via LDS, add bias, store bf16 ----
  float* scr = reinterpret_cast<float*>(smem);
  const int slot = (wq * 64 + lane) * 97;  // 96 floats + 1 pad -> conflict-free
#pragma unroll
  for (int p = 0; p < 2; ++p) {
    __syncthreads();
    if (kh == 1) {
#pragma unroll
      for (int mi = 0; mi < 4; ++mi)
#pragma unroll
        for (int ni = 0; ni < 6; ++ni)
#pragma unroll
          for (int r = 0; r < 4; ++r)
            scr[slot + (mi * 6 + ni) * 4 + r] = acc[p * 4 + mi][ni][r];
    }
    __syncthreads();
    if (kh == 0) {
#pragma unroll
      for (int ni = 0; ni < 6; ++ni) {
        const int cc = N0 + wn * 96 + ni * 16 + l15;
        const float bn = bias[cc];
#pragma unroll
        for (int mi = 0; mi < 4; ++mi) {
          const int gmi = p * 4 + mi;
          const int r0 = M0 + wm * 128 + gmi * 16 + quad * 4;
#pragma unroll
          for (int r = 0; r < 4; ++r)
            C[(size_t)(r0 + r) * 3072 + cc] =
                f2bf(acc[gmi][ni][r] + scr[slot + (mi * 6 + ni) * 4 + r] + bn);
        }
      }
    }
  }
}

// ---------------------------------------------------------------------------
// attn_tok: UNCHANGED (control).
// ---------------------------------------------------------------------------
__global__ __launch_bounds__(256, 4) void attn_tok(const ushort_t* __restrict__ C,
                                                   float* __restrict__ out) {
  __shared__ uint4 kv4[4][256];  // [wave][k rows 0..127 | v rows 128..255]
  const int tid = threadIdx.x;
  const int lane = tid & 63, wv = tid >> 6;
  const int t = blockIdx.x * 4 + wv;
  const ushort_t* Crow = C + (size_t)t * 3072;

  const uint4* src = reinterpret_cast<const uint4*>(Crow + 1024);
#pragma unroll
  for (int r = 0; r < 4; ++r) kv4[wv][r * 64 + lane] = src[r * 64 + lane];
  __syncthreads();

  const uint4 q01 = *reinterpret_cast<const uint4*>(Crow + lane * 16);
  const uint4 q23 = *reinterpret_cast<const uint4*>(Crow + lane * 16 + 8);
  float qa[8], qb[8];
  qa[0] = bflo(q01.x); qa[1] = bfhi(q01.x); qa[2] = bflo(q01.y); qa[3] = bfhi(q01.y);
  qa[4] = bflo(q01.z); qa[5] = bfhi(q01.z); qa[6] = bflo(q01.w); qa[7] = bfhi(q01.w);
  qb[0] = bflo(q23.x); qb[1] = bfhi(q23.x); qb[2] = bflo(q23.y); qb[3] = bfhi(q23.y);
  qb[4] = bflo(q23.z); qb[5] = bfhi(q23.z); qb[6] = bflo(q23.w); qb[7] = bfhi(q23.w);

  const uint4* kvw = kv4[wv];
  const float sc = 0.08838834764831845f;  // 1/sqrt(128)
  float oa[8], ob[8];
#pragma unroll
  for (int j = 0; j < 8; ++j) { oa[j] = 0.f; ob[j] = 0.f; }
  float l0 = 0.f, l1 = 0.f;

#pragma unroll 2
  for (int e = 0; e < 128; ++e) {
    const uint4 kr = kvw[e];
    float kf[8];
    kf[0] = bflo(kr.x); kf[1] = bfhi(kr.x); kf[2] = bflo(kr.y); kf[3] = bfhi(kr.y);
    kf[4] = bflo(kr.z); kf[5] = bfhi(kr.z); kf[6] = bflo(kr.w); kf[7] = bfhi(kr.w);
    float s0 = 0.f, s1 = 0.f;
#pragma unroll
    for (int j = 0; j < 8; ++j) { s0 += qa[j] * kf[j]; s1 += qb[j] * kf[j]; }
    const float p0 = __expf(s0 * sc);
    const float p1 = __expf(s1 * sc);
    l0 += p0; l1 += p1;
    const uint4 vr = kvw[128 + e];
    float vf[8];
    vf[0] = bflo(vr.x); vf[1] = bfhi(vr.x); vf[2] = bflo(vr.y); vf[3] = bfhi(vr.y);
    vf[4] = bflo(vr.z); vf[5] = bfhi(vr.z); vf[6] = bflo(vr.w); vf[7] = bfhi(vr.w);
#pragma unroll
    for (int j = 0; j < 8; ++j) { oa[j] += p0 * vf[j]; ob[j] += p1 * vf[j]; }
  }

  const float i0 = 1.f / l0, i1 = 1.f / l1;
  float4* dst = reinterpret_cast<float4*>(out + (size_t)t * 4096 + (size_t)lane * 64);
#pragma unroll
  for (int j = 0; j < 8; ++j) {
    const float w = oa[j] * i0;
    dst[j] = make_float4(w, w, w, w);
  }
#pragma unroll
  for (int j = 0; j < 8; ++j) {
    const float w = ob[j] * i1;
    dst[8 + j] = make_float4(w, w, w, w);
  }
}

extern "C" void kernel_launch(void* const* d_in, const int* in_sizes, int n_in,
                              void* d_out, int out_size, void* d_ws, size_t ws_size,
                              hipStream_t stream) {
  const float* x  = (const float*)d_in[0];  // [2,2048,4096] fp32
  const float* Wq = (const float*)d_in[1];  // [4096,128,32]
  const float* bq = (const float*)d_in[2];  // [128,32]
  const float* Wk = (const float*)d_in[3];  // [4096,128,8]
  const float* bk = (const float*)d_in[4];  // [128,8]
  const float* Wv = (const float*)d_in[5];  // [4096,128,8]
  const float* bv = (const float*)d_in[6];  // [128,8]
  float* out = (float*)d_out;               // [4096][4096] fp32 = 64 MB

  // d_out doubles as scratch until attn_tok overwrites it:
  //   [0,32M): Ax bf16; [32M,56M): Wt bf16; [56M,+12K): bias fp32.
  // d_ws: Cmat bf16 [4096][3072] (24 MB).
  ushort_t* Ax = (ushort_t*)d_out;
  ushort_t* Wt = Ax + (size_t)4096 * 4096;
  float* bias = (float*)(Wt + (size_t)3072 * 4096);
  ushort_t* Cmat = (ushort_t*)d_ws;

  prep_all<<<dim3(11276), 256, 0, stream>>>(x, Wq, Wk, Wv, bq, bk, bv, Ax, Wt, bias);
  gemm_qkv<<<dim3(256), 512, 0, stream>>>(Ax, Wt, bias, Cmat);
  attn_tok<<<dim3(1024), 256, 0, stream>>>(Cmat, out);
}

// Round 6
// 345.934 us; speedup vs baseline: 3.1271x; 3.1271x over previous
//
#include <hip/hip_runtime.h>
#include <cstdint>

typedef unsigned short ushort_t;
typedef __bf16 bf16x8 __attribute__((ext_vector_type(8)));
typedef float f32x4 __attribute__((ext_vector_type(4)));
typedef float f32x2 __attribute__((ext_vector_type(2)));

__device__ __forceinline__ unsigned short f2bf(float f) {
  unsigned u = __builtin_bit_cast(unsigned, f);
  u += 0x7FFFu + ((u >> 16) & 1u);   // RNE
  return (unsigned short)(u >> 16);
}
__device__ __forceinline__ float bflo(unsigned u) {  // low bf16 -> f32
  return __builtin_bit_cast(float, u << 16);
}
__device__ __forceinline__ float bfhi(unsigned u) {  // high bf16 -> f32
  return __builtin_bit_cast(float, u & 0xFFFF0000u);
}
// async global->LDS, 16B/lane; LDS dest = wave-uniform base + lane*16
__device__ __forceinline__ void gld16(const void* g, void* l) {
  auto* gp = reinterpret_cast<const __attribute__((address_space(1))) unsigned*>(
      reinterpret_cast<uintptr_t>(g));
  auto* lp = reinterpret_cast<__attribute__((address_space(3))) unsigned*>(
      reinterpret_cast<uintptr_t>(l));
  __builtin_amdgcn_global_load_lds(gp, lp, 16, 0, 0);
}

// ---------------------------------------------------------------------------
// prep_all: UNCHANGED (control).
// ---------------------------------------------------------------------------
__global__ __launch_bounds__(256) void prep_all(
    const float* __restrict__ x, const float* __restrict__ Wq,
    const float* __restrict__ Wk, const float* __restrict__ Wv,
    const float* __restrict__ bq, const float* __restrict__ bk,
    const float* __restrict__ bv, ushort_t* __restrict__ Ax,
    ushort_t* __restrict__ Wt, float* __restrict__ bias) {
  __shared__ ushort_t red[64][65];
  const int b = blockIdx.x;
  const int tid = threadIdx.x;
  if (b < 3072) {
    const int ntile = b % 48, ktile = b / 48;
    const int n0 = ntile * 64, k0 = ktile * 64;
    if (ntile < 16) {
      for (int i = tid; i < 64 * 64; i += 256) {
        const int kk = i >> 6, nn = i & 63;
        const float4 w = *reinterpret_cast<const float4*>(
            Wq + (size_t)(k0 + kk) * 4096 + (size_t)(n0 + nn) * 4);
        red[kk][nn] = f2bf(w.x + w.y + w.z + w.w);
      }
    } else {
      const float* W = (ntile < 32) ? Wk : Wv;
      const int nb = (ntile < 32) ? (n0 - 1024) : (n0 - 2048);
      for (int i = tid; i < 64 * 64; i += 256) {
        const int kk = i >> 6, nn = i & 63;
        red[kk][nn] = f2bf(W[(size_t)(k0 + kk) * 1024 + nb + nn]);
      }
    }
    __syncthreads();
    for (int i = tid; i < 64 * 64; i += 256) {
      const int kk = i & 63, nn = i >> 6;  // coalesced along k
      Wt[(size_t)(n0 + nn) * 4096 + k0 + kk] = red[kk][nn];
    }
  } else if (b < 11264) {
    const size_t i = ((size_t)(b - 3072) * 256 + tid) * 8;
    const float4 a = *reinterpret_cast<const float4*>(x + i);
    const float4 c = *reinterpret_cast<const float4*>(x + i + 4);
    union { ushort_t u[8]; uint4 v; } pk;
    pk.u[0] = f2bf(a.x); pk.u[1] = f2bf(a.y); pk.u[2] = f2bf(a.z); pk.u[3] = f2bf(a.w);
    pk.u[4] = f2bf(c.x); pk.u[5] = f2bf(c.y); pk.u[6] = f2bf(c.z); pk.u[7] = f2bf(c.w);
    *reinterpret_cast<uint4*>(Ax + i) = pk.v;
  } else {
    const int n = (b - 11264) * 256 + tid;  // 0..3071
    float v;
    if (n < 1024) {
      const float4 w = *reinterpret_cast<const float4*>(bq + (size_t)n * 4);
      v = w.x + w.y + w.z + w.w;
    } else if (n < 2048) {
      v = bk[n - 1024];
    } else {
      v = bv[n - 2048];
    }
    bias[n] = v;
  }
}

// ---------------------------------------------------------------------------
// gemm_qkv v5 (R4, VERIFIED 97.2-98.0 us twice): 256x192 tile, BK=64,
// 8 waves = 2M x 2N x 2Khalf, per-wave 128x96 out. R5's intra-wave frag
// double-buffer SPILLED (2.2 GB scratch writes) -- launch_bounds(512,2)
// caps regs at 256/wave; 192-reg acc + 112-reg frags don't fit. Reverted.
// ---------------------------------------------------------------------------
#define WAITV0() asm volatile("s_waitcnt vmcnt(0)" ::: "memory")
#define BARRIER()                         \
  do {                                    \
    __builtin_amdgcn_s_barrier();         \
    asm volatile("" ::: "memory");        \
    __builtin_amdgcn_sched_barrier(0);    \
  } while (0)

__global__ __launch_bounds__(512, 2) void gemm_qkv(const ushort_t* __restrict__ A,
                                                   const ushort_t* __restrict__ Bt,
                                                   const float* __restrict__ bias,
                                                   ushort_t* __restrict__ C) {
  __shared__ char smem[114688];                      // As 64K | Bs 48K ; reused as f32 scratch
  ushort_t* AsBuf = reinterpret_cast<ushort_t*>(smem);            // [2][16384]
  ushort_t* BsBuf = reinterpret_cast<ushort_t*>(smem + 65536);    // [2][12288]
  const int tid = threadIdx.x;
  const int lane = tid & 63, wave = tid >> 6;  // 8 waves

  // bijective XCD swizzle (256 blocks, 256 % 8 == 0)
  const int id = blockIdx.x;
  const int wg = (id & 7) * 32 + (id >> 3);
  const int M0 = (wg >> 4) * 256, N0 = (wg & 15) * 192;

  const int rik = lane >> 3;         // row within 8-row chunk
  const int gch = (lane & 7) ^ rik;  // pre-swizzled global k-chunk (involution)
  const ushort_t* aG = A + (size_t)(M0 + wave * 32 + rik) * 4096 + gch * 8;
  const ushort_t* bG = Bt + (size_t)(N0 + wave * 24 + rik) * 4096 + gch * 8;

  const int kh = wave & 1, wq = wave >> 1;   // k-half | output quadrant
  const int wm = wq >> 1, wn = wq & 1;       // 2M x 2N
  const int quad = lane >> 4, l15 = lane & 15;

  // fragment LDS byte offsets: row*128 + phys_chunk*16; row&7 == l15&7
  const int ch = ((kh * 4 + quad) ^ (l15 & 7)) * 16;
  const int abase = (wm * 128 + l15) * 128 + ch;  // + mi*2048
  const int bbase = (wn * 96 + l15) * 128 + ch;   // + ni*2048

  f32x4 acc[8][6];
  const f32x4 z = {0.f, 0.f, 0.f, 0.f};
#pragma unroll
  for (int mi = 0; mi < 8; ++mi)
#pragma unroll
    for (int ni = 0; ni < 6; ++ni) acc[mi][ni] = z;

  auto stage = [&](int bb, int kt) {
    const int ko = kt * 64;
    ushort_t* asb = AsBuf + bb * 16384;
    ushort_t* bsb = BsBuf + bb * 12288;
#pragma unroll
    for (int q = 0; q < 4; ++q)  // A rows wave*32 + q*8 + rik
      gld16(aG + ko + (size_t)q * (8 * 4096), asb + (wave * 4 + q) * 512);
#pragma unroll
    for (int q = 0; q < 3; ++q)  // B rows wave*24 + q*8 + rik
      gld16(bG + ko + (size_t)q * (8 * 4096), bsb + (wave * 3 + q) * 512);
  };

  // prologue: stage tile 0 into buf0, publish.
  stage(0, 0);
  WAITV0();
  BARRIER();

  for (int kt = 0; kt < 64; ++kt) {
    const int bb = kt & 1;
    if (kt < 63) stage(bb ^ 1, kt + 1);  // front-load next tile's 7 loads
    const char* ab = reinterpret_cast<const char*>(AsBuf + bb * 16384);
    const char* bbp = reinterpret_cast<const char*>(BsBuf + bb * 12288);
    bf16x8 af[8];
#pragma unroll
    for (int mi = 0; mi < 8; ++mi)
      af[mi] = *reinterpret_cast<const bf16x8*>(ab + abase + mi * 2048);
#pragma unroll
    for (int ni = 0; ni < 6; ++ni) {
      const bf16x8 bf = *reinterpret_cast<const bf16x8*>(bbp + bbase + ni * 2048);
      __builtin_amdgcn_s_setprio(1);
#pragma unroll
      for (int mi = 0; mi < 8; ++mi)
        acc[mi][ni] =
            __builtin_amdgcn_mfma_f32_16x16x32_bf16(af[mi], bf, acc[mi][ni], 0, 0, 0);
      __builtin_amdgcn_s_setprio(0);
    }
    // gate: own 7 loads had the whole compute phase to land.
    WAITV0();
    BARRIER();
  }

  // ---- epilogue: reduce k-halves via LDS, add bias, store bf16 ----
  float* scr = reinterpret_cast<float*>(smem);
  const int slot = (wq * 64 + lane) * 97;  // 96 floats + 1 pad -> conflict-free
#pragma unroll
  for (int p = 0; p < 2; ++p) {
    __syncthreads();
    if (kh == 1) {
#pragma unroll
      for (int mi = 0; mi < 4; ++mi)
#pragma unroll
        for (int ni = 0; ni < 6; ++ni)
#pragma unroll
          for (int r = 0; r < 4; ++r)
            scr[slot + (mi * 6 + ni) * 4 + r] = acc[p * 4 + mi][ni][r];
    }
    __syncthreads();
    if (kh == 0) {
#pragma unroll
      for (int ni = 0; ni < 6; ++ni) {
        const int cc = N0 + wn * 96 + ni * 16 + l15;
        const float bn = bias[cc];
#pragma unroll
        for (int mi = 0; mi < 4; ++mi) {
          const int gmi = p * 4 + mi;
          const int r0 = M0 + wm * 128 + gmi * 16 + quad * 4;
#pragma unroll
          for (int r = 0; r < 4; ++r)
            C[(size_t)(r0 + r) * 3072 + cc] =
                f2bf(acc[gmi][ni][r] + scr[slot + (mi * 6 + ni) * 4 + r] + bn);
        }
      }
    }
  }
}

// ---------------------------------------------------------------------------
// attn_tok v4: same math/layout as v3 (verified), three changes:
//  1. KV staging via global_load_lds (no VGPR round-trip, 4 gld16/wave)
//  2. NO __syncthreads: each wave reads only kv4[wv] (own-wave vmcnt(0)
//     is the only ordering needed for global_load_lds -> ds_read)
//  3. packed f32x2 arithmetic: lane's two rows (d0,d0+1) as 2-vectors ->
//     8 pk_fma replace 16 scalar fma in both QK and PV inner loops
// ---------------------------------------------------------------------------
__global__ __launch_bounds__(256, 4) void attn_tok(const ushort_t* __restrict__ C,
                                                   float* __restrict__ out) {
  __shared__ uint4 kv4[4][256];  // [wave][k rows 0..127 | v rows 128..255]
  const int tid = threadIdx.x;
  const int lane = tid & 63, wv = tid >> 6;
  const int t = blockIdx.x * 4 + wv;
  const ushort_t* Crow = C + (size_t)t * 3072;

  // stage 4 KB of K|V via async global->LDS: lane's 16B at base + lane*16
  const ushort_t* kvg = Crow + 1024;
#pragma unroll
  for (int r = 0; r < 4; ++r)
    gld16(kvg + r * 512 + lane * 8, &kv4[wv][r * 64]);

  const uint4 q01 = *reinterpret_cast<const uint4*>(Crow + lane * 16);
  const uint4 q23 = *reinterpret_cast<const uint4*>(Crow + lane * 16 + 8);
  f32x2 q2[8];
  q2[0] = f32x2{bflo(q01.x), bflo(q23.x)};
  q2[1] = f32x2{bfhi(q01.x), bfhi(q23.x)};
  q2[2] = f32x2{bflo(q01.y), bflo(q23.y)};
  q2[3] = f32x2{bfhi(q01.y), bfhi(q23.y)};
  q2[4] = f32x2{bflo(q01.z), bflo(q23.z)};
  q2[5] = f32x2{bfhi(q01.z), bfhi(q23.z)};
  q2[6] = f32x2{bflo(q01.w), bflo(q23.w)};
  q2[7] = f32x2{bfhi(q01.w), bfhi(q23.w)};

  WAITV0();  // own wave's 4 staging loads landed; no cross-wave sharing

  const uint4* kvw = kv4[wv];
  const float sc = 0.08838834764831845f;  // 1/sqrt(128)
  f32x2 o2[8];
#pragma unroll
  for (int j = 0; j < 8; ++j) o2[j] = f32x2{0.f, 0.f};
  f32x2 lsum = f32x2{0.f, 0.f};

#pragma unroll 2
  for (int e = 0; e < 128; ++e) {
    const uint4 kr = kvw[e];
    float kf[8];
    kf[0] = bflo(kr.x); kf[1] = bfhi(kr.x); kf[2] = bflo(kr.y); kf[3] = bfhi(kr.y);
    kf[4] = bflo(kr.z); kf[5] = bfhi(kr.z); kf[6] = bflo(kr.w); kf[7] = bfhi(kr.w);
    f32x2 s = f32x2{0.f, 0.f};
#pragma unroll
    for (int j = 0; j < 8; ++j) s += q2[j] * kf[j];
    const f32x2 p = f32x2{__expf(s.x * sc), __expf(s.y * sc)};
    lsum += p;
    const uint4 vr = kvw[128 + e];
    float vf[8];
    vf[0] = bflo(vr.x); vf[1] = bfhi(vr.x); vf[2] = bflo(vr.y); vf[3] = bfhi(vr.y);
    vf[4] = bflo(vr.z); vf[5] = bfhi(vr.z); vf[6] = bflo(vr.w); vf[7] = bfhi(vr.w);
#pragma unroll
    for (int j = 0; j < 8; ++j) o2[j] += p * vf[j];
  }

  const float i0 = 1.f / lsum.x, i1 = 1.f / lsum.y;
  float4* dst = reinterpret_cast<float4*>(out + (size_t)t * 4096 + (size_t)lane * 64);
#pragma unroll
  for (int j = 0; j < 8; ++j) {
    const float w = o2[j].x * i0;
    dst[j] = make_float4(w, w, w, w);
  }
#pragma unroll
  for (int j = 0; j < 8; ++j) {
    const float w = o2[j].y * i1;
    dst[8 + j] = make_float4(w, w, w, w);
  }
}

extern "C" void kernel_launch(void* const* d_in, const int* in_sizes, int n_in,
                              void* d_out, int out_size, void* d_ws, size_t ws_size,
                              hipStream_t stream) {
  const float* x  = (const float*)d_in[0];  // [2,2048,4096] fp32
  const float* Wq = (const float*)d_in[1];  // [4096,128,32]
  const float* bq = (const float*)d_in[2];  // [128,32]
  const float* Wk = (const float*)d_in[3];  // [4096,128,8]
  const float* bk = (const float*)d_in[4];  // [128,8]
  const float* Wv = (const float*)d_in[5];  // [4096,128,8]
  const float* bv = (const float*)d_in[6];  // [128,8]
  float* out = (float*)d_out;               // [4096][4096] fp32 = 64 MB

  // d_out doubles as scratch until attn_tok overwrites it:
  //   [0,32M): Ax bf16; [32M,56M): Wt bf16; [56M,+12K): bias fp32.
  // d_ws: Cmat bf16 [4096][3072] (24 MB).
  ushort_t* Ax = (ushort_t*)d_out;
  ushort_t* Wt = Ax + (size_t)4096 * 4096;
  float* bias = (float*)(Wt + (size_t)3072 * 4096);
  ushort_t* Cmat = (ushort_t*)d_ws;

  prep_all<<<dim3(11276), 256, 0, stream>>>(x, Wq, Wk, Wv, bq, bk, bv, Ax, Wt, bias);
  gemm_qkv<<<dim3(256), 512, 0, stream>>>(Ax, Wt, bias, Cmat);
  attn_tok<<<dim3(1024), 256, 0, stream>>>(Cmat, out);
}